// Round 7
// baseline (108.770 us; speedup 1.0000x reference)
//
#include <hip/hip_runtime.h>
#include <hip/hip_fp16.h>
#include <cstdint>

#define HH 128
#define WW 128
#define NBATCH 2
#define CIN 256
#define COUT 256
#define DGN 4
#define K2 9
#define HW (HH*WW)
#define KTOT (K2*CIN)          // 2304, K index = tap*256 + c
#define NKB (KTOT/32)          // 72 k-steps
#define NMT (COUT/16)          // 16 m-tiles
#define NITER 36               // k-step pairs

typedef __attribute__((ext_vector_type(8))) short short8;
typedef __attribute__((ext_vector_type(8))) _Float16 f16x8;
typedef __attribute__((ext_vector_type(4))) float f32x4;

struct __align__(16) H2x4 { __half2 h[4]; };

#define LGKM0() asm volatile("s_waitcnt lgkmcnt(0)" ::: "memory")
#define RAWBAR() do { LGKM0(); __builtin_amdgcn_s_barrier(); } while (0)
#define SB0() __builtin_amdgcn_sched_barrier(0)

static __device__ __forceinline__ unsigned short f2h_u(float f) {
    _Float16 h = (_Float16)f;
    return __builtin_bit_cast(unsigned short, h);
}

// ---- prologue 1: NCHW fp32 -> NHWC fp16 (xT[n][p][c], 512B per pixel) ----
__global__ __launch_bounds__(256) void tr_kernel(const float* __restrict__ x,
                                                 unsigned short* __restrict__ xT) {
    __shared__ float tile[64][65];
    const int b  = blockIdx.x;
    const int pt = b & 255;
    const int ct = (b >> 8) & 3;
    const int n  = b >> 10;
    const int p0 = pt * 64, c0 = ct * 64;
    const float* xn = x + (size_t)n * CIN * HW;
    const int tid = threadIdx.x;
    {
        const int tx = tid & 63, ty = tid >> 6;
        #pragma unroll
        for (int i = 0; i < 16; ++i) {
            int ch = i * 4 + ty;
            tile[ch][tx] = xn[(size_t)(c0 + ch) * HW + p0 + tx];
        }
    }
    __syncthreads();
    char* xb = (char*)xT + (size_t)n * HW * 512;
    {
        const int cx = tid & 31, pq = tid >> 5;
        #pragma unroll
        for (int i = 0; i < 8; ++i) {
            int p = i * 8 + pq;
            unsigned lo = f2h_u(tile[2 * cx][p]);
            unsigned hi = f2h_u(tile[2 * cx + 1][p]);
            *(unsigned*)(xb + (size_t)(p0 + p) * 512 + c0 * 2 + cx * 4) = lo | (hi << 16);
        }
    }
}

// ---- prologue 2: weights -> A-fragment layout (fp16) ----
// wA dword ((kb*16+mt)*64+lane)*4+r : k = kb*32+(lane>>4)*8+2r{,+1}, m = mt*16+(lane&15)
__global__ void wa_kernel(const float* __restrict__ w, unsigned int* __restrict__ wA) {
    int t = blockIdx.x * blockDim.x + threadIdx.x;
    if (t >= NKB * NMT * 64 * 4) return;
    int r  = t & 3;
    int l  = (t >> 2) & 63;
    int mt = (t >> 8) & 15;
    int kb = t >> 12;
    int m  = mt * 16 + (l & 15);
    int k0 = kb * 32 + (l >> 4) * 8 + r * 2;
    unsigned int pk = 0;
    #pragma unroll
    for (int e = 0; e < 2; ++e) {
        int k = k0 + e;
        int tap = k >> 8;
        int c = k & 255;
        float v = w[(size_t)m * (CIN * K2) + c * 9 + tap];
        pk |= ((unsigned int)f2h_u(v)) << (16 * e);
    }
    wA[t] = pk;
}

// ---- main: 8 waves, 64 px, M=256; fp16 blend; raw barriers; 2-ahead gathers ----
__global__ __launch_bounds__(512, 4) void deform_mfma_kernel(
    const unsigned short* __restrict__ xT,
    const float* __restrict__ shape,
    const float* __restrict__ wo,
    const short8* __restrict__ wAf,
    float* __restrict__ out)
{
    __shared__ __align__(16) char smem[71680];
    int4*   s_ofs = (int4*)smem;                       // [36*64]        36864 B
    uint2*  s_cw  = (uint2*)(smem + 36864);            // [36*64]        18432 B
    short8* bufB  = (short8*)(smem + 36864 + 18432);   // [2][2][4][64]  16384 B

    const int tid = threadIdx.x;
    const int bid = blockIdx.x;                    // 512 blocks
    const int tile = (bid & 7) * 64 + (bid >> 3);  // XCD-chunked swizzle
    const int wh = tile & 1;
    const int h  = (tile >> 1) & 127;
    const int n  = tile >> 8;

    // ---- coord phase: 36 (dg,tap) x 64 px -> corner tables ----
    for (int s = tid; s < DGN * K2 * 64; s += 512) {
        int p64 = s & 63;
        int dgk = s >> 6;
        int tap = dgk % 9;
        int w   = wh * 64 + p64;
        float s0 = shape[((size_t)(n * 2 + 0)) * HW + h * WW + w];
        float s1 = shape[((size_t)(n * 2 + 1)) * HW + h * WW + w];
        float dy = wo[dgk * 4 + 0] * s0 + wo[dgk * 4 + 1] * s1;
        float dx = wo[dgk * 4 + 2] * s0 + wo[dgk * 4 + 3] * s1;
        float py  = (float)(h + (tap / 3) - 1) + dy;
        float pxf = (float)(w + (tap % 3) - 1) + dx;
        float y0f = floorf(py), x0f = floorf(pxf);
        float ly = py - y0f, lx = pxf - x0f;
        int y0 = (int)y0f, x0 = (int)x0f;
        float wgt[4] = {(1.f - ly) * (1.f - lx), (1.f - ly) * lx,
                        ly * (1.f - lx),         ly * lx};
        int ofsv[4]; unsigned cwh[4];
        #pragma unroll
        for (int j = 0; j < 4; ++j) {
            int yi = y0 + (j >> 1);
            int xi = x0 + (j & 1);
            bool valid = (yi >= 0) && (yi < HH) && (xi >= 0) && (xi < WW);
            int yc = min(max(yi, 0), HH - 1);
            int xc = min(max(xi, 0), WW - 1);
            ofsv[j] = (yc * WW + xc) * 512;
            cwh[j] = f2h_u(valid ? wgt[j] : 0.0f);
        }
        s_ofs[s] = (int4){ofsv[0], ofsv[1], ofsv[2], ofsv[3]};
        s_cw[s]  = (uint2){cwh[0] | (cwh[1] << 16), cwh[2] | (cwh[3] << 16)};
    }
    __syncthreads();

    const int wave = tid >> 6;
    const int lane = tid & 63;
    const int pcol = lane & 15;
    const int quad = lane >> 4;
    const int kbh  = wave >> 2;          // this wave builds k-half kbh
    const int pxg  = wave & 3;           // ... for pixel group pxg
    const int bpx  = pxg * 16 + pcol;    // build pixel (block-local)
    const int q16  = quad * 16;          // channel byte sub-offset

    const char* xb = (const char*)xT + (size_t)n * HW * 512;

    f32x4 acc[2][4];
    #pragma unroll
    for (int a = 0; a < 2; ++a)
        #pragma unroll
        for (int b = 0; b < 4; ++b) acc[a][b] = (f32x4){0.f, 0.f, 0.f, 0.f};

    struct Gset { short8 v[4]; __half2 w01, w23; };

    // issue gathers for k-pair i2 (corner tables -> 4 x 16B scattered loads)
    auto issueG = [&](int i2, Gset& g) {
        int dgk = (i2 & 3) * 9 + (i2 >> 2);
        int4  of = s_ofs[dgk * 64 + bpx];
        uint2 cw = s_cw[dgk * 64 + bpx];
        g.w01 = __builtin_bit_cast(__half2, cw.x);
        g.w23 = __builtin_bit_cast(__half2, cw.y);
        int cq = 2 * (i2 & 3) + kbh;
        const char* cb = xb + (size_t)(cq * 64 + q16);
        g.v[0] = *(const short8*)(cb + of.x);
        g.v[1] = *(const short8*)(cb + of.y);
        g.v[2] = *(const short8*)(cb + of.z);
        g.v[3] = *(const short8*)(cb + of.w);
    };
    // blend with packed fp16 fma, write fragment into buf slot
    auto blendW = [&](const Gset& g, int slot) {
        __half2 w0 = __low2half2(g.w01), w1 = __high2half2(g.w01);
        __half2 w2 = __low2half2(g.w23), w3 = __high2half2(g.w23);
        H2x4 a0 = __builtin_bit_cast(H2x4, g.v[0]);
        H2x4 a1 = __builtin_bit_cast(H2x4, g.v[1]);
        H2x4 a2 = __builtin_bit_cast(H2x4, g.v[2]);
        H2x4 a3 = __builtin_bit_cast(H2x4, g.v[3]);
        H2x4 r;
        #pragma unroll
        for (int j = 0; j < 4; ++j) {
            __half2 t = __hmul2(w0, a0.h[j]);
            t = __hfma2(w1, a1.h[j], t);
            t = __hfma2(w2, a2.h[j], t);
            t = __hfma2(w3, a3.h[j], t);
            r.h[j] = t;
        }
        bufB[((slot * 2 + kbh) * 4 + pxg) * 64 + lane] = __builtin_bit_cast(short8, r);
    };
    auto loadA = [&](int i, short8 A[4]) {
        const short8* wa = wAf + (size_t)(2 * i) * (NMT * 64) + (wave * 2) * 64 + lane;
        A[0] = wa[0];
        A[1] = wa[64];
        A[2] = wa[NMT * 64];
        A[3] = wa[NMT * 64 + 64];
    };
    auto mfmaStep = [&](int i, const short8 A[4]) {
        const int cur = i & 1;
        __builtin_amdgcn_s_setprio(1);
        #pragma unroll
        for (int kb2 = 0; kb2 < 2; ++kb2) {
            f16x8 a0 = __builtin_bit_cast(f16x8, A[kb2 * 2 + 0]);
            f16x8 a1 = __builtin_bit_cast(f16x8, A[kb2 * 2 + 1]);
            #pragma unroll
            for (int pg = 0; pg < 4; ++pg) {
                f16x8 bfr = __builtin_bit_cast(f16x8, bufB[((cur * 2 + kb2) * 4 + pg) * 64 + lane]);
                acc[0][pg] = __builtin_amdgcn_mfma_f32_16x16x32_f16(a0, bfr, acc[0][pg], 0, 0, 0);
                acc[1][pg] = __builtin_amdgcn_mfma_f32_16x16x32_f16(a1, bfr, acc[1][pg], 0, 0, 0);
            }
        }
        __builtin_amdgcn_s_setprio(0);
    };

    // ---- pipeline prologue: gathers for 0 and 1 in flight, A(0)/A(1) issued ----
    Gset Ga, Gb;
    short8 Aa[4], Ab[4];
    issueG(0, Ga);
    loadA(0, Aa);
    issueG(1, Gb);
    loadA(1, Ab);
    blendW(Ga, 0);                 // waits gathers(0) only
    RAWBAR();

    // ---- main loop: 18 x 2 sub-iterations; gathers issued 2 sub-iters ahead ----
    for (int t = 0; t < NITER; t += 2) {
        // sub-iter t: mfma(t) from Aa/buf[t&1]; blend(t+1) from Gb (issued at t-1)
        if (t + 2 < NITER) issueG(t + 2, Ga);
        SB0();
        mfmaStep(t, Aa);
        SB0();
        if (t + 2 < NITER) loadA(t + 2, Aa);
        blendW(Gb, (t + 1) & 1);
        RAWBAR();
        // sub-iter t+1: mfma(t+1) from Ab/buf[(t+1)&1]; blend(t+2) from Ga
        if (t + 3 < NITER) issueG(t + 3, Gb);
        SB0();
        mfmaStep(t + 1, Ab);
        SB0();
        if (t + 3 < NITER) loadA(t + 3, Ab);
        if (t + 2 < NITER) blendW(Ga, (t + 2) & 1);
        RAWBAR();
    }

    // ---- epilogue: per-wave LDS transpose for coalesced stores ----
    float* s_ep = (float*)(smem + wave * 4352);   // [16][68] per wave (private region)
    const int w0 = wh * 64;
    #pragma unroll
    for (int mtl = 0; mtl < 2; ++mtl) {
        #pragma unroll
        for (int pg = 0; pg < 4; ++pg)
            #pragma unroll
            for (int r = 0; r < 4; ++r)
                s_ep[(quad * 4 + r) * 68 + pg * 16 + pcol] = fmaxf(acc[mtl][pg][r], 0.f);
        LGKM0();
        SB0();
        #pragma unroll
        for (int p4 = 0; p4 < 4; ++p4) {
            int mr = p4 * 4 + quad;
            f32x4 v = *(const f32x4*)&s_ep[mr * 68 + pcol * 4];
            int m = wave * 32 + mtl * 16 + mr;
            *(f32x4*)(out + ((size_t)(n * COUT + m)) * HW + h * WW + w0 + pcol * 4) = v;
        }
        LGKM0();
        SB0();
    }
}

extern "C" void kernel_launch(void* const* d_in, const int* in_sizes, int n_in,
                              void* d_out, int out_size, void* d_ws, size_t ws_size,
                              hipStream_t stream) {
    const float* x        = (const float*)d_in[0];
    const float* shape    = (const float*)d_in[1];
    const float* w_offset = (const float*)d_in[2];
    const float* w_adapt  = (const float*)d_in[3];
    float* out = (float*)d_out;

    unsigned int*   wA = (unsigned int*)d_ws;                       // 1.18 MB
    unsigned short* xT = (unsigned short*)((char*)d_ws + 0x130000); // 16.78 MB

    tr_kernel<<<NBATCH * 4 * 256, 256, 0, stream>>>(x, xT);
    int wa_elems = NKB * NMT * 64 * 4;
    wa_kernel<<<(wa_elems + 255) / 256, 256, 0, stream>>>(w_adapt, wA);
    deform_mfma_kernel<<<NBATCH * HH * 2, 512, 0, stream>>>(
        xT, shape, w_offset, (const short8*)wA, out);
}

// Round 8
// 102.871 us; speedup vs baseline: 1.0574x; 1.0574x over previous
//
#include <hip/hip_runtime.h>
#include <hip/hip_fp16.h>
#include <cstdint>

#define HH 128
#define WW 128
#define NBATCH 2
#define CIN 256
#define COUT 256
#define DGN 4
#define K2 9
#define HW (HH*WW)
#define KTOT (K2*CIN)          // 2304, K index = tap*256 + c
#define NKS (KTOT/16)          // 144 k16-slices
#define NMT32 (COUT/32)        // 8 m-tiles of 32
#define NITER 36               // k-pairs (K=64 each)

typedef __attribute__((ext_vector_type(8))) short short8;
typedef __attribute__((ext_vector_type(8))) _Float16 f16x8;
typedef __attribute__((ext_vector_type(16))) float f32x16;

struct __align__(16) H2x4 { __half2 h[4]; };

#define LGKM0() asm volatile("s_waitcnt lgkmcnt(0)" ::: "memory")
#define RAWBAR() do { LGKM0(); __builtin_amdgcn_s_barrier(); } while (0)
#define SB0() __builtin_amdgcn_sched_barrier(0)

static __device__ __forceinline__ unsigned short f2h_u(float f) {
    _Float16 h = (_Float16)f;
    return __builtin_bit_cast(unsigned short, h);
}

// ---- prologue 1: NCHW fp32 -> NHWC fp16 (xT[n][p][c], 512B per pixel) ----
__global__ __launch_bounds__(256) void tr_kernel(const float* __restrict__ x,
                                                 unsigned short* __restrict__ xT) {
    __shared__ float tile[64][65];
    const int b  = blockIdx.x;
    const int pt = b & 255;
    const int ct = (b >> 8) & 3;
    const int n  = b >> 10;
    const int p0 = pt * 64, c0 = ct * 64;
    const float* xn = x + (size_t)n * CIN * HW;
    const int tid = threadIdx.x;
    {
        const int tx = tid & 63, ty = tid >> 6;
        #pragma unroll
        for (int i = 0; i < 16; ++i) {
            int ch = i * 4 + ty;
            tile[ch][tx] = xn[(size_t)(c0 + ch) * HW + p0 + tx];
        }
    }
    __syncthreads();
    char* xb = (char*)xT + (size_t)n * HW * 512;
    {
        const int cx = tid & 31, pq = tid >> 5;
        #pragma unroll
        for (int i = 0; i < 8; ++i) {
            int p = i * 8 + pq;
            unsigned lo = f2h_u(tile[2 * cx][p]);
            unsigned hi = f2h_u(tile[2 * cx + 1][p]);
            *(unsigned*)(xb + (size_t)(p0 + p) * 512 + c0 * 2 + cx * 4) = lo | (hi << 16);
        }
    }
}

// ---- prologue 2: weights -> 32x32x16 A-fragment layout (fp16) ----
// frag (ks, mt): dword ((ks*8+mt)*64 + l)*4 + r holds k = ks*16 + (l>>5)*8 + 2r{,+1},
// m = mt*32 + (l&31);  W[m][k] = w_adapt[m][c][tap], tap = k>>8, c = k&255
__global__ void wa_kernel(const float* __restrict__ w, unsigned int* __restrict__ wA) {
    int t = blockIdx.x * blockDim.x + threadIdx.x;
    if (t >= NKS * NMT32 * 64 * 4) return;
    int r  = t & 3;
    int l  = (t >> 2) & 63;
    int mt = (t >> 8) & 7;
    int ks = t >> 11;
    int m  = mt * 32 + (l & 31);
    int k0 = ks * 16 + (l >> 5) * 8 + r * 2;
    unsigned int pk = 0;
    #pragma unroll
    for (int e = 0; e < 2; ++e) {
        int k = k0 + e;
        int tap = k >> 8;
        int c = k & 255;
        float v = w[(size_t)m * (CIN * K2) + c * 9 + tap];
        pk |= ((unsigned int)f2h_u(v)) << (16 * e);
    }
    wA[t] = pk;
}

// ---- main: 8 waves, 64 px, M=256; 32x32x16 MFMA; 4-slot bufB; barrier per 2 k-pairs ----
__global__ __launch_bounds__(512, 4) void deform_mfma_kernel(
    const unsigned short* __restrict__ xT,
    const float* __restrict__ shape,
    const float* __restrict__ wo,
    const short8* __restrict__ wAf,
    float* __restrict__ out)
{
    __shared__ __align__(16) char smem[51200];
    float*  s_pp = (float*)smem;               // [36][64][2]   18432 B
    short8* bufB = (short8*)(smem + 18432);    // [4][8][64]    32768 B

    const int tid = threadIdx.x;
    const int bid = blockIdx.x;                    // 512 blocks
    const int tile = (bid & 7) * 64 + (bid >> 3);  // XCD-chunked swizzle
    const int wh = tile & 1;
    const int h  = (tile >> 1) & 127;
    const int n  = tile >> 8;

    // ---- coord phase: 36 (dg,tap) x 64 px -> (py,px) ----
    for (int s = tid; s < DGN * K2 * 64; s += 512) {
        int p64 = s & 63;
        int dgk = s >> 6;
        int tap = dgk % 9;
        int w   = wh * 64 + p64;
        float s0 = shape[((size_t)(n * 2 + 0)) * HW + h * WW + w];
        float s1 = shape[((size_t)(n * 2 + 1)) * HW + h * WW + w];
        float dy = wo[dgk * 4 + 0] * s0 + wo[dgk * 4 + 1] * s1;
        float dx = wo[dgk * 4 + 2] * s0 + wo[dgk * 4 + 3] * s1;
        s_pp[(dgk * 64 + p64) * 2 + 0] = (float)(h + (tap / 3) - 1) + dy;
        s_pp[(dgk * 64 + p64) * 2 + 1] = (float)(w + (tap % 3) - 1) + dx;
    }
    __syncthreads();

    const int wave = tid >> 6;
    const int lane = tid & 63;
    // builder role: px-half pxh, k16-slice ksl
    const int pxh  = wave & 1;
    const int ksl  = wave >> 1;              // 0..3
    const int bpx  = pxh * 32 + (lane & 31); // build pixel (block-local)
    const int koct = lane >> 5;              // channel octet within slice
    // consumer role: m-tile32 = wave, both px-halves
    const int mt   = wave;

    const char* xb = (const char*)xT + (size_t)n * HW * 512;

    f32x16 acc0, acc1;
    #pragma unroll
    for (int r = 0; r < 16; ++r) { acc0[r] = 0.f; acc1[r] = 0.f; }

    struct Gset { short8 v[4]; __half2 w01, w23; };

    // issue gathers for k-pair i2 (corner math recomputed from s_pp)
    auto issueG = [&](int i2, Gset& g) {
        int dgk = (i2 & 3) * 9 + (i2 >> 2);
        float py = s_pp[(dgk * 64 + bpx) * 2 + 0];
        float px = s_pp[(dgk * 64 + bpx) * 2 + 1];
        float y0f = floorf(py), x0f = floorf(px);
        float ly = py - y0f, lx = px - x0f;
        int y0 = (int)y0f, x0 = (int)x0f;
        float wgt[4] = {(1.f - ly) * (1.f - lx), (1.f - ly) * lx,
                        ly * (1.f - lx),         ly * lx};
        int ofs[4]; unsigned short cwh[4];
        #pragma unroll
        for (int j = 0; j < 4; ++j) {
            int yi = y0 + (j >> 1);
            int xi = x0 + (j & 1);
            bool valid = (yi >= 0) && (yi < HH) && (xi >= 0) && (xi < WW);
            int yc = min(max(yi, 0), HH - 1);
            int xc = min(max(xi, 0), WW - 1);
            ofs[j] = (yc * WW + xc) * 512;
            cwh[j] = f2h_u(valid ? wgt[j] : 0.0f);
        }
        g.w01 = __builtin_bit_cast(__half2, (unsigned)(cwh[0] | ((unsigned)cwh[1] << 16)));
        g.w23 = __builtin_bit_cast(__half2, (unsigned)(cwh[2] | ((unsigned)cwh[3] << 16)));
        // channel byte offset: c = 64*dg + 16*ksl + 8*koct  ->  bytes 128*dg + 32*ksl + 16*koct
        const char* cb = xb + (size_t)(128 * (i2 & 3) + 32 * ksl + 16 * koct);
        g.v[0] = *(const short8*)(cb + ofs[0]);
        g.v[1] = *(const short8*)(cb + ofs[1]);
        g.v[2] = *(const short8*)(cb + ofs[2]);
        g.v[3] = *(const short8*)(cb + ofs[3]);
    };
    // blend with packed fp16 fma, write fragment (pxh*4 + ksl) into buf slot
    auto blendW = [&](const Gset& g, int slot) {
        __half2 w0 = __low2half2(g.w01), w1 = __high2half2(g.w01);
        __half2 w2 = __low2half2(g.w23), w3 = __high2half2(g.w23);
        H2x4 a0 = __builtin_bit_cast(H2x4, g.v[0]);
        H2x4 a1 = __builtin_bit_cast(H2x4, g.v[1]);
        H2x4 a2 = __builtin_bit_cast(H2x4, g.v[2]);
        H2x4 a3 = __builtin_bit_cast(H2x4, g.v[3]);
        H2x4 r;
        #pragma unroll
        for (int j = 0; j < 4; ++j) {
            __half2 t = __hmul2(w0, a0.h[j]);
            t = __hfma2(w1, a1.h[j], t);
            t = __hfma2(w2, a2.h[j], t);
            t = __hfma2(w3, a3.h[j], t);
            r.h[j] = t;
        }
        bufB[(slot * 8 + pxh * 4 + ksl) * 64 + lane] = __builtin_bit_cast(short8, r);
    };
    // A fragments for k-pair i: 4 k16-slices for this wave's m-tile
    auto loadA = [&](int i, short8 A[4]) {
        const short8* wa = wAf + ((size_t)(i * 4) * NMT32 + mt) * 64 + lane;
        A[0] = wa[0];
        A[1] = wa[NMT32 * 64];
        A[2] = wa[2 * NMT32 * 64];
        A[3] = wa[3 * NMT32 * 64];
    };
    auto mfmaStep = [&](int i, const short8 A[4]) {
        const int slot = i & 3;
        __builtin_amdgcn_s_setprio(1);
        #pragma unroll
        for (int s = 0; s < 4; ++s) {
            f16x8 a  = __builtin_bit_cast(f16x8, A[s]);
            f16x8 b0 = __builtin_bit_cast(f16x8, bufB[(slot * 8 + s) * 64 + lane]);
            f16x8 b1 = __builtin_bit_cast(f16x8, bufB[(slot * 8 + 4 + s) * 64 + lane]);
            acc0 = __builtin_amdgcn_mfma_f32_32x32x16_f16(a, b0, acc0, 0, 0, 0);
            acc1 = __builtin_amdgcn_mfma_f32_32x32x16_f16(a, b1, acc1, 0, 0, 0);
        }
        __builtin_amdgcn_s_setprio(0);
    };

    // ---- pipeline prologue: build slots 0,1; preload A(0),A(1) ----
    Gset G;
    short8 Aa[4], Ab[4];
    issueG(0, G);
    loadA(0, Aa);
    loadA(1, Ab);
    blendW(G, 0);
    issueG(1, G);
    blendW(G, 1);
    RAWBAR();

    // ---- main loop: 18 phases, each = 2 k-pairs, one barrier ----
    for (int t = 0; t < NITER; t += 2) {
        const bool bld = (t + 2 < NITER);
        if (bld) issueG(t + 2, G);
        SB0();
        mfmaStep(t, Aa);
        SB0();
        if (bld) {
            blendW(G, (t + 2) & 3);
            issueG(t + 3, G);
            loadA(t + 2, Aa);
        }
        SB0();
        mfmaStep(t + 1, Ab);
        SB0();
        if (bld) {
            blendW(G, (t + 3) & 3);
            loadA(t + 3, Ab);
        }
        RAWBAR();
    }

    // ---- epilogue: direct coalesced stores (32x32 C/D layout) ----
    // col = lane&31 (pixel), row = (reg&3) + 8*(reg>>2) + 4*(lane>>5)
    const int w0 = wh * 64;
    const int cl = lane & 31;
    const int rb = 4 * (lane >> 5);
    float* on = out + ((size_t)(n * COUT + mt * 32)) * HW + h * WW + w0;
    #pragma unroll
    for (int reg = 0; reg < 16; ++reg) {
        int m = (reg & 3) + 8 * (reg >> 2) + rb;
        on[(size_t)m * HW + cl]      = fmaxf(acc0[reg], 0.f);
        on[(size_t)m * HW + 32 + cl] = fmaxf(acc1[reg], 0.f);
    }
}

extern "C" void kernel_launch(void* const* d_in, const int* in_sizes, int n_in,
                              void* d_out, int out_size, void* d_ws, size_t ws_size,
                              hipStream_t stream) {
    const float* x        = (const float*)d_in[0];
    const float* shape    = (const float*)d_in[1];
    const float* w_offset = (const float*)d_in[2];
    const float* w_adapt  = (const float*)d_in[3];
    float* out = (float*)d_out;

    unsigned int*   wA = (unsigned int*)d_ws;                       // 1.18 MB
    unsigned short* xT = (unsigned short*)((char*)d_ws + 0x130000); // 16.78 MB

    tr_kernel<<<NBATCH * 4 * 256, 256, 0, stream>>>(x, xT);
    int wa_elems = NKS * NMT32 * 64 * 4;
    wa_kernel<<<(wa_elems + 255) / 256, 256, 0, stream>>>(w_adapt, wA);
    deform_mfma_kernel<<<NBATCH * HH * 2, 512, 0, stream>>>(
        xT, shape, w_offset, (const short8*)wA, out);
}

// Round 9
// 86.140 us; speedup vs baseline: 1.2627x; 1.1942x over previous
//
#include <hip/hip_runtime.h>
#include <hip/hip_fp16.h>
#include <cstdint>

#define HH 128
#define WW 128
#define NBATCH 2
#define CIN 256
#define COUT 256
#define DGN 4
#define K2 9
#define HW (HH*WW)
#define KTOT (K2*CIN)          // 2304, K index = dg*576 + tap*64 + c (dg-major!)
#define NKS (KTOT/16)          // 144 k16-slices
#define NMT32 (COUT/32)        // 8 m-tiles of 32
// window: rows h-2..h+2 (5), cols w0-2..w0+65 (68)
#define WROWS 5
#define WCOLS 68
#define WPX (WROWS*WCOLS)      // 340 pixels, 128B each -> 43520 B

typedef __attribute__((ext_vector_type(8))) short short8;
typedef __attribute__((ext_vector_type(8))) _Float16 f16x8;
typedef __attribute__((ext_vector_type(16))) float f32x16;

struct __align__(16) H2x4 { __half2 h[4]; };

#define LGKM0() asm volatile("s_waitcnt lgkmcnt(0)" ::: "memory")
#define RAWBAR() do { LGKM0(); __builtin_amdgcn_s_barrier(); } while (0)

static __device__ __forceinline__ unsigned short f2h_u(float f) {
    _Float16 h = (_Float16)f;
    return __builtin_bit_cast(unsigned short, h);
}

// ---- prologue 1: NCHW fp32 -> NHWC fp16 (xT[n][p][c], 512B per pixel) ----
__global__ __launch_bounds__(256) void tr_kernel(const float* __restrict__ x,
                                                 unsigned short* __restrict__ xT) {
    __shared__ float tile[64][65];
    const int b  = blockIdx.x;
    const int pt = b & 255;
    const int ct = (b >> 8) & 3;
    const int n  = b >> 10;
    const int p0 = pt * 64, c0 = ct * 64;
    const float* xn = x + (size_t)n * CIN * HW;
    const int tid = threadIdx.x;
    {
        const int tx = tid & 63, ty = tid >> 6;
        #pragma unroll
        for (int i = 0; i < 16; ++i) {
            int ch = i * 4 + ty;
            tile[ch][tx] = xn[(size_t)(c0 + ch) * HW + p0 + tx];
        }
    }
    __syncthreads();
    char* xb = (char*)xT + (size_t)n * HW * 512;
    {
        const int cx = tid & 31, pq = tid >> 5;
        #pragma unroll
        for (int i = 0; i < 8; ++i) {
            int p = i * 8 + pq;
            unsigned lo = f2h_u(tile[2 * cx][p]);
            unsigned hi = f2h_u(tile[2 * cx + 1][p]);
            *(unsigned*)(xb + (size_t)(p0 + p) * 512 + c0 * 2 + cx * 4) = lo | (hi << 16);
        }
    }
}

// ---- prologue 2: weights -> 32x32x16 A-fragments, dg-major K ordering ----
// k' = dg*576 + tap*64 + c' ; W[m][k'] = w_adapt[m][dg*64+c'][tap]
// dword ((ks*8+mt)*64 + l)*4 + r : k' = ks*16 + (l>>5)*8 + 2r{,+1}, m = mt*32+(l&31)
__global__ void wa_kernel(const float* __restrict__ w, unsigned int* __restrict__ wA) {
    int t = blockIdx.x * blockDim.x + threadIdx.x;
    if (t >= NKS * NMT32 * 64 * 4) return;
    int r  = t & 3;
    int l  = (t >> 2) & 63;
    int mt = (t >> 8) & 7;
    int ks = t >> 11;
    int m  = mt * 32 + (l & 31);
    int k0 = ks * 16 + (l >> 5) * 8 + r * 2;
    unsigned int pk = 0;
    #pragma unroll
    for (int e = 0; e < 2; ++e) {
        int k = k0 + e;                 // dg-major index
        int dg  = k / 576;
        int rem = k - dg * 576;
        int tap = rem >> 6;
        int c   = dg * 64 + (rem & 63);
        float v = w[(size_t)m * (CIN * K2) + c * 9 + tap];
        pk |= ((unsigned int)f2h_u(v)) << (16 * e);
    }
    wA[t] = pk;
}

// ---- main: 8 waves, 64 px, M=256; per-dg LDS window staging; LDS gathers ----
__global__ __launch_bounds__(512, 4) void deform_mfma_kernel(
    const unsigned short* __restrict__ xT,
    const float* __restrict__ shape,
    const float* __restrict__ wo,
    const short8* __restrict__ wAf,
    float* __restrict__ out)
{
    __shared__ __align__(16) char smem[78336];
    float*  s_pp  = (float*)smem;                      // [36][64][2]  18432 B
    char*   s_stg = smem + 18432;                      // [340 px][128B] 43520 B (swizzled)
    short8* bufB  = (short8*)(smem + 18432 + 43520);   // [2][8][64]   16384 B

    const int tid = threadIdx.x;
    const int bid = blockIdx.x;                    // 512 blocks
    const int tile = (bid & 7) * 64 + (bid >> 3);  // XCD-chunked swizzle
    const int wh = tile & 1;
    const int h  = (tile >> 1) & 127;
    const int n  = tile >> 8;
    const int w0 = wh * 64;
    const int ybase = h - 2, xbase = w0 - 2;

    // ---- coord phase: 36 (dg,tap) x 64 px -> (py,px) ----
    for (int s = tid; s < DGN * K2 * 64; s += 512) {
        int p64 = s & 63;
        int dgk = s >> 6;
        int tap = dgk % 9;
        int w   = w0 + p64;
        float s0 = shape[((size_t)(n * 2 + 0)) * HW + h * WW + w];
        float s1 = shape[((size_t)(n * 2 + 1)) * HW + h * WW + w];
        float dy = wo[dgk * 4 + 0] * s0 + wo[dgk * 4 + 1] * s1;
        float dx = wo[dgk * 4 + 2] * s0 + wo[dgk * 4 + 3] * s1;
        s_pp[(dgk * 64 + p64) * 2 + 0] = (float)(h + (tap / 3) - 1) + dy;
        s_pp[(dgk * 64 + p64) * 2 + 1] = (float)(w + (tap % 3) - 1) + dx;
    }
    __syncthreads();

    const int wave = tid >> 6;
    const int lane = tid & 63;
    // builder role: px-half pxh, k16-slice ksl
    const int pxh  = wave & 1;
    const int ksl  = wave >> 1;              // 0..3
    const int bpx  = pxh * 32 + (lane & 31); // build pixel (block-local)
    const int koct = lane >> 5;              // channel octet within slice
    const int chnk = 2 * ksl + koct;         // 16B chunk within 128B dg-row (0..7)
    // consumer role: m-tile32 = wave
    const int mt   = wave;

    const char* xb = (const char*)xT + (size_t)n * HW * 512;

    f32x16 acc0, acc1;
    #pragma unroll
    for (int r = 0; r < 16; ++r) { acc0[r] = 0.f; acc1[r] = 0.f; }

    // ---- stage dg window: 340 px x 128B, swizzled chunks ----
    auto stageDG = [&](int dg) {
        const char* xsrc = xb + dg * 128;
        for (int i = tid; i < WPX * 8; i += 512) {
            int chunk = i & 7;
            int px = i >> 3;                    // 0..339
            int sy = (unsigned)px / WCOLS;
            int sx = px - sy * WCOLS;
            int r = min(max(ybase + sy, 0), HH - 1);
            int c = min(max(xbase + sx, 0), WW - 1);
            short8 v = *(const short8*)(xsrc + (size_t)(r * WW + c) * 512 + chunk * 16);
            *(short8*)(s_stg + px * 128 + ((chunk ^ (px & 7)) * 16)) = v;
        }
    };

    // ---- build one k-pair's B fragment from the LDS window (global fallback) ----
    auto buildKP = [&](int dg, int tap, int slot) {
        int dgk = dg * 9 + tap;
        float py  = s_pp[(dgk * 64 + bpx) * 2 + 0];
        float pxf = s_pp[(dgk * 64 + bpx) * 2 + 1];
        float y0f = floorf(py), x0f = floorf(pxf);
        float ly = py - y0f, lx = pxf - x0f;
        int y0 = (int)y0f, x0 = (int)x0f;
        float wgt[4] = {(1.f - ly) * (1.f - lx), (1.f - ly) * lx,
                        ly * (1.f - lx),         ly * lx};
        short8 v[4]; unsigned short cwh[4];
        #pragma unroll
        for (int j = 0; j < 4; ++j) {
            int yi = y0 + (j >> 1);
            int xi = x0 + (j & 1);
            bool valid = (yi >= 0) && (yi < HH) && (xi >= 0) && (xi < WW);
            int yc = min(max(yi, 0), HH - 1);
            int xc = min(max(xi, 0), WW - 1);
            cwh[j] = f2h_u(valid ? wgt[j] : 0.0f);
            int sy = yc - ybase, sx = xc - xbase;
            if ((unsigned)sy < (unsigned)WROWS && (unsigned)sx < (unsigned)WCOLS) {
                int pl = sy * WCOLS + sx;
                v[j] = *(const short8*)(s_stg + pl * 128 + ((chnk ^ (pl & 7)) * 16));
            } else {
                v[j] = *(const short8*)(xb + (size_t)(yc * WW + xc) * 512 + dg * 128 + chnk * 16);
            }
        }
        __half2 w0h = __builtin_bit_cast(__half2, (unsigned)(cwh[0] | ((unsigned)cwh[1] << 16)));
        __half2 w2h = __builtin_bit_cast(__half2, (unsigned)(cwh[2] | ((unsigned)cwh[3] << 16)));
        __half2 c0 = __low2half2(w0h), c1 = __high2half2(w0h);
        __half2 c2 = __low2half2(w2h), c3 = __high2half2(w2h);
        H2x4 a0 = __builtin_bit_cast(H2x4, v[0]);
        H2x4 a1 = __builtin_bit_cast(H2x4, v[1]);
        H2x4 a2 = __builtin_bit_cast(H2x4, v[2]);
        H2x4 a3 = __builtin_bit_cast(H2x4, v[3]);
        H2x4 r;
        #pragma unroll
        for (int j = 0; j < 4; ++j) {
            __half2 t = __hmul2(c0, a0.h[j]);
            t = __hfma2(c1, a1.h[j], t);
            t = __hfma2(c2, a2.h[j], t);
            t = __hfma2(c3, a3.h[j], t);
            r.h[j] = t;
        }
        bufB[(slot * 8 + pxh * 4 + ksl) * 64 + lane] = __builtin_bit_cast(short8, r);
    };

    auto loadA = [&](int i, short8 A[4]) {
        const short8* wa = wAf + ((size_t)(i * 4) * NMT32 + mt) * 64 + lane;
        A[0] = wa[0];
        A[1] = wa[NMT32 * 64];
        A[2] = wa[2 * NMT32 * 64];
        A[3] = wa[3 * NMT32 * 64];
    };
    auto mfmaStep = [&](int slot, const short8 A[4]) {
        __builtin_amdgcn_s_setprio(1);
        #pragma unroll
        for (int s = 0; s < 4; ++s) {
            f16x8 a  = __builtin_bit_cast(f16x8, A[s]);
            f16x8 b0 = __builtin_bit_cast(f16x8, bufB[(slot * 8 + s) * 64 + lane]);
            f16x8 b1 = __builtin_bit_cast(f16x8, bufB[(slot * 8 + 4 + s) * 64 + lane]);
            acc0 = __builtin_amdgcn_mfma_f32_32x32x16_f16(a, b0, acc0, 0, 0, 0);
            acc1 = __builtin_amdgcn_mfma_f32_32x32x16_f16(a, b1, acc1, 0, 0, 0);
        }
        __builtin_amdgcn_s_setprio(0);
    };

    // ---- main: 4 dg phases x (stage + 9 taps, ping-pong bufB) ----
    short8 A[4];
    for (int dg = 0; dg < DGN; ++dg) {
        stageDG(dg);
        __syncthreads();                 // stage visible to all waves
        buildKP(dg, 0, 0);
        RAWBAR();
        for (int tap = 0; tap < 9; ++tap) {
            loadA(dg * 9 + tap, A);
            if (tap < 8) buildKP(dg, tap + 1, (tap + 1) & 1);
            mfmaStep(tap & 1, A);
            RAWBAR();                    // bufB slot ready for next iter; stage reads done
        }
    }

    // ---- epilogue: direct coalesced stores (32x32 C/D layout) ----
    // col = lane&31 (pixel), row = (reg&3) + 8*(reg>>2) + 4*(lane>>5)
    const int cl = lane & 31;
    const int rb = 4 * (lane >> 5);
    float* on = out + ((size_t)(n * COUT + mt * 32)) * HW + h * WW + w0;
    #pragma unroll
    for (int reg = 0; reg < 16; ++reg) {
        int m = (reg & 3) + 8 * (reg >> 2) + rb;
        on[(size_t)m * HW + cl]      = fmaxf(acc0[reg], 0.f);
        on[(size_t)m * HW + 32 + cl] = fmaxf(acc1[reg], 0.f);
    }
}

extern "C" void kernel_launch(void* const* d_in, const int* in_sizes, int n_in,
                              void* d_out, int out_size, void* d_ws, size_t ws_size,
                              hipStream_t stream) {
    const float* x        = (const float*)d_in[0];
    const float* shape    = (const float*)d_in[1];
    const float* w_offset = (const float*)d_in[2];
    const float* w_adapt  = (const float*)d_in[3];
    float* out = (float*)d_out;

    unsigned int*   wA = (unsigned int*)d_ws;                       // 1.18 MB
    unsigned short* xT = (unsigned short*)((char*)d_ws + 0x130000); // 16.78 MB

    tr_kernel<<<NBATCH * 4 * 256, 256, 0, stream>>>(x, xT);
    int wa_elems = NKS * NMT32 * 64 * 4;
    wa_kernel<<<(wa_elems + 255) / 256, 256, 0, stream>>>(w_adapt, wA);
    deform_mfma_kernel<<<NBATCH * HH * 2, 512, 0, stream>>>(
        xT, shape, w_offset, (const short8*)wA, out);
}